// Round 2
// baseline (279.384 us; speedup 1.0000x reference)
//
#include <hip/hip_runtime.h>

#define T_LEN 256
#define D_IN 4
#define SPR 8                       // timesteps per barrier round
#define NROUND (T_LEN / SPR + 2)    // 34: layer skew 0..2

typedef __fp16 h8 __attribute__((ext_vector_type(8)));
typedef __fp16 cvt2_t __attribute__((ext_vector_type(2)));
typedef float float4v __attribute__((ext_vector_type(4)));

struct CellW { const float *Wih, *Whh, *bih, *bhh; };
struct Params { CellW c[6]; const float* y; float* hout; };

__device__ __forceinline__ float fexp2(float x) { return __builtin_amdgcn_exp2f(x); }
__device__ __forceinline__ float frcp(float x)  { return __builtin_amdgcn_rcpf(x); }
__device__ __forceinline__ int packh(float a, float b) {
    cvt2_t p = __builtin_amdgcn_cvt_pkrtz(a, b);
    return __builtin_bit_cast(int, p);
}
__device__ __forceinline__ h8 mk8(int a, int b, int c, int d) {
    int4 v; v.x = a; v.y = b; v.z = c; v.w = d;
    return __builtin_bit_cast(h8, v);
}

// K=32 MFMA: one instruction per gate. A = [Whh-cols | Wprev-cols] with the
// SAME per-lane element convention used for B = {own-h packs, prev packs}.
// D layout: lane(n,Q) reg r = row 4Q+r, col n -> recurrence needs 2 packs.
#define MFMA32(a, b, c) __builtin_amdgcn_mfma_f32_16x16x32_f16(a, b, c, 0, 0, 0)

// Activation for the lane's 4 units. pi,pf,po pre-scaled by -log2e, pg by
// -2log2e (folded into A/bias). rcps PAIRED across the 4 independent unit
// chains: R=rcp(a*b); 1/a=R*b; 1/b=R*a.  6 rcp + 20 exp2 per lane-step.
// Overflow audit (|pre| <= ~10.5): F<=2^16, P<=2^47, Dh<=2^46 (ec clamp
// 2^30); all pair products < 2^94 << 2^127.
__device__ __forceinline__ void act4(const float4v& pi, const float4v& pf,
                                     const float4v& pg, const float4v& po,
                                     float* cc, float* h) {
    float F[4], P[4], NG[4];
#pragma unroll
    for (int j = 0; j < 4; ++j) {
        float ei = fexp2(pi[j]);
        float ef = fexp2(pf[j]);
        float eg = fexp2(pg[j]);
        F[j]  = 1.f + ef;                      // sigmoid(f) denominator
        P[j]  = (1.f + ei) * (1.f + eg);       // i*g joint denominator
        NG[j] = 1.f - eg;                      // tanh(g) numerator
    }
    float RF01 = frcp(F[0] * F[1]);
    float RF23 = frcp(F[2] * F[3]);
    float RP01 = frcp(P[0] * P[1]);
    float RP23 = frcp(P[2] * P[3]);
    float f0 = RF01 * F[1], f1 = RF01 * F[0];
    float f2 = RF23 * F[3], f3 = RF23 * F[2];
    float ig0 = NG[0] * P[1] * RP01, ig1 = NG[1] * P[0] * RP01;
    float ig2 = NG[2] * P[3] * RP23, ig3 = NG[3] * P[2] * RP23;

    float NO[4], Dh[4];
    cc[0] = fmaf(f0, cc[0], ig0);
    cc[1] = fmaf(f1, cc[1], ig1);
    cc[2] = fmaf(f2, cc[2], ig2);
    cc[3] = fmaf(f3, cc[3], ig3);
    const float K2 = -2.8853900817779268f;     // -2*log2e
#pragma unroll
    for (int j = 0; j < 4; ++j) {
        float eo = fexp2(po[j]);
        float ec = fexp2(fminf(cc[j] * K2, 30.f));
        NO[j] = 1.f - ec;
        Dh[j] = (1.f + eo) * (1.f + ec);
    }
    float RH01 = frcp(Dh[0] * Dh[1]);
    float RH23 = frcp(Dh[2] * Dh[3]);
    h[0] = NO[0] * Dh[1] * RH01;
    h[1] = NO[1] * Dh[0] * RH01;
    h[2] = NO[2] * Dh[3] * RH23;
    h[3] = NO[3] * Dh[2] * RH23;
}

// Block = 3 waves = 3 layers; each wave now owns TWO 16-chain tiles of the
// same layer+dir (weights shared, state duplicated). 256 blocks -> 3 waves/CU
// -> exactly 1 wave/SIMD; the two tiles' independent dependency chains
// interleave inside one instruction stream to fill trans-latency stalls.
__global__ void __launch_bounds__(192)
__attribute__((amdgpu_waves_per_eu(1, 1)))
lstm_chain_kernel(Params p)
{
    __shared__ int2 lds_h0[2][2][SPR][64];   // tile0 [producer][parity][k][lane]
    __shared__ int2 lds_h1[2][2][SPR][64];   // tile1            (16KB each)

    const int w = threadIdx.x >> 6;     // wave = layer
    const int L = threadIdx.x & 63;
    const int n = L & 15;               // batch col
    const int Q = L >> 4;

    const int tid = blockIdx.x;
    const int dir = tid & 1;
    const int b0  = (tid >> 1) * 32;    // tiles at b0 and b0+16

    const CellW cw = p.c[dir * 3 + w];
    const float LOG2E = 1.4426950408889634f;

    // ---- fused A-frags (shared by both tiles): elems 0-3 = Whh k=4Q..4Q+3,
    // elems 4-7 = prev-side (Wih for w>0; x-weights (Q==0)/zero for w==0) ----
    h8 A8[4];
    float4v bs[4];
#pragma unroll
    for (int g = 0; g < 4; ++g) {
        const float s = (g == 2) ? -2.f * LOG2E : -LOG2E;
        const int row = g * 16 + n;
        float vh[4], vp[4];
#pragma unroll
        for (int i = 0; i < 4; ++i) {
            const int k = 4 * Q + i;
            vh[i] = cw.Whh[row * 16 + k];
            vp[i] = (w == 0) ? ((Q == 0) ? cw.Wih[row * D_IN + k] : 0.f)
                             : cw.Wih[row * 16 + k];
        }
        A8[g] = mk8(packh(vh[0] * s, vh[1] * s), packh(vh[2] * s, vh[3] * s),
                    packh(vp[0] * s, vp[1] * s), packh(vp[2] * s, vp[3] * s));
        const int u0 = g * 16 + 4 * Q;   // bias: reg r -> unit 4Q+r
        float4 bi = *(const float4*)&cw.bih[u0];
        float4 bh = *(const float4*)&cw.bhh[u0];
        bs[g] = (float4v){(bi.x+bh.x)*s, (bi.y+bh.y)*s, (bi.z+bh.z)*s, (bi.w+bh.w)*s};
    }

    // ---- x prefetch (wave 0, lanes L<16 = chain n, both tiles) ----
    const float* yb0 = p.y + (size_t)b0 * (T_LEN * D_IN);
    const float* yb1 = p.y + (size_t)(b0 + 16) * (T_LEN * D_IN);
    float4 xn0[SPR], xn1[SPR];
    if (w == 0 && L < 16) {
#pragma unroll
        for (int k = 0; k < SPR; ++k) {
            const int tt = dir ? (T_LEN - 1 - k) : k;
            xn0[k] = *(const float4*)(yb0 + ((size_t)n * T_LEN + tt) * D_IN);
            xn1[k] = *(const float4*)(yb1 + ((size_t)n * T_LEN + tt) * D_IN);
        }
    }

    float cc0[4] = {0.f, 0.f, 0.f, 0.f};
    float cc1[4] = {0.f, 0.f, 0.f, 0.f};
    float h0[4] = {0.f, 0.f, 0.f, 0.f};
    float h1[4] = {0.f, 0.f, 0.f, 0.f};
    int hp00 = 0, hp01 = 0;             // packed own h, tile0
    int hp10 = 0, hp11 = 0;             // packed own h, tile1

#pragma unroll 1
    for (int s = 0; s < NROUND; ++s) {
        __syncthreads();
        const int t0 = (s - w) * SPR;
        if (t0 < 0 || t0 >= T_LEN) continue;

        // wave 0: commit prefetched x to packed B-dwords, start next loads
        int xp0[SPR][2], xp1[SPR][2];
        if (w == 0) {
            if (L < 16) {
#pragma unroll
                for (int k = 0; k < SPR; ++k) {
                    xp0[k][0] = packh(xn0[k].x, xn0[k].y);
                    xp0[k][1] = packh(xn0[k].z, xn0[k].w);
                    xp1[k][0] = packh(xn1[k].x, xn1[k].y);
                    xp1[k][1] = packh(xn1[k].z, xn1[k].w);
                }
                if (t0 + SPR < T_LEN) {
#pragma unroll
                    for (int k = 0; k < SPR; ++k) {
                        const int t = t0 + SPR + k;
                        const int tt = dir ? (T_LEN - 1 - t) : t;
                        xn0[k] = *(const float4*)(yb0 + ((size_t)n * T_LEN + tt) * D_IN);
                        xn1[k] = *(const float4*)(yb1 + ((size_t)n * T_LEN + tt) * D_IN);
                    }
                }
            } else {
#pragma unroll
                for (int k = 0; k < SPR; ++k) {
                    xp0[k][0] = 0; xp0[k][1] = 0;
                    xp1[k][0] = 0; xp1[k][1] = 0;
                }
            }
        }

        // hoist all cross-layer h reads (latency off the chain)
        int2 hv0[SPR], hv1[SPR];
        if (w >= 1) {
#pragma unroll
            for (int k = 0; k < SPR; ++k) {
                hv0[k] = lds_h0[w - 1][(s + 1) & 1][k][L];
                hv1[k] = lds_h1[w - 1][(s + 1) & 1][k][L];
            }
        }

#pragma unroll
        for (int k = 0; k < SPR; ++k) {
            const int pd00 = (w == 0) ? xp0[k][0] : hv0[k].x;
            const int pd01 = (w == 0) ? xp0[k][1] : hv0[k].y;
            const int pd10 = (w == 0) ? xp1[k][0] : hv1[k].x;
            const int pd11 = (w == 0) ? xp1[k][1] : hv1[k].y;
            const h8 b80 = mk8(hp00, hp01, pd00, pd01);
            const h8 b81 = mk8(hp10, hp11, pd10, pd11);
            float4v pi0 = MFMA32(A8[0], b80, bs[0]);
            float4v pf0 = MFMA32(A8[1], b80, bs[1]);
            float4v pg0 = MFMA32(A8[2], b80, bs[2]);
            float4v po0 = MFMA32(A8[3], b80, bs[3]);
            float4v pi1 = MFMA32(A8[0], b81, bs[0]);
            float4v pf1 = MFMA32(A8[1], b81, bs[1]);
            float4v pg1 = MFMA32(A8[2], b81, bs[2]);
            float4v po1 = MFMA32(A8[3], b81, bs[3]);
            act4(pi0, pf0, pg0, po0, cc0, h0);
            act4(pi1, pf1, pg1, po1, cc1, h1);
            hp00 = packh(h0[0], h0[1]);
            hp01 = packh(h0[2], h0[3]);
            hp10 = packh(h1[0], h1[1]);
            hp11 = packh(h1[2], h1[3]);
            if (w < 2) {
                int2 hw0; hw0.x = hp00; hw0.y = hp01;
                int2 hw1; hw1.x = hp10; hw1.y = hp11;
                lds_h0[w][s & 1][k][L] = hw0;
                lds_h1[w][s & 1][k][L] = hw1;
            }
        }
    }

    // wave 2 holds h3(T-1): lane (n,Q) has units 4Q..4Q+3, batch n / n+16
    if (w == 2) {
        float4v ho0 = {h0[0], h0[1], h0[2], h0[3]};
        float4v ho1 = {h1[0], h1[1], h1[2], h1[3]};
        *(float4v*)&p.hout[(size_t)(b0 + n) * 32 + dir * 16 + 4 * Q] = ho0;
        *(float4v*)&p.hout[(size_t)(b0 + 16 + n) * 32 + dir * 16 + 4 * Q] = ho1;
    }
}

__global__ void out_proj_kernel(const float* __restrict__ ws,
                                const float* __restrict__ Wout,
                                const float* __restrict__ bout,
                                float* __restrict__ out, int B)
{
    int idx = blockIdx.x * blockDim.x + threadIdx.x;
    if (idx >= B * 4) return;
    int b = idx >> 2, o = idx & 3;
    float acc = bout[o];
    const float* h = ws + (size_t)b * 32;
    const float* w = Wout + o * 32;
#pragma unroll
    for (int m = 0; m < 32; ++m) acc = fmaf(h[m], w[m], acc);
    out[idx] = acc;
}

extern "C" void kernel_launch(void* const* d_in, const int* in_sizes, int n_in,
                              void* d_out, int out_size, void* d_ws, size_t ws_size,
                              hipStream_t stream)
{
    const int B = in_sizes[0] / (T_LEN * D_IN); // 4096

    Params p;
    for (int s = 0; s < 6; ++s) {
        p.c[s].Wih = (const float*)d_in[1 + 4 * s];
        p.c[s].Whh = (const float*)d_in[2 + 4 * s];
        p.c[s].bih = (const float*)d_in[3 + 4 * s];
        p.c[s].bhh = (const float*)d_in[4 + 4 * s];
    }
    p.y = (const float*)d_in[0];
    p.hout = (float*)d_ws;

    const int tiles = (B / 32) * 2;          // 2x16 chains per block, both dirs
    lstm_chain_kernel<<<tiles, 192, 0, stream>>>(p);

    const float* Wout = (const float*)d_in[25];
    const float* bout = (const float*)d_in[26];
    out_proj_kernel<<<(B * 4 + 255) / 256, 256, 0, stream>>>(
        (const float*)d_ws, Wout, bout, (float*)d_out, B);
}

// Round 4
// 274.263 us; speedup vs baseline: 1.0187x; 1.0187x over previous
//
#include <hip/hip_runtime.h>

#define T_LEN 256
#define D_IN 4
#define SPR 8                       // timesteps per barrier round
#define NROUND (T_LEN / SPR + 2)    // 34: layer skew 0..2

typedef __fp16 h4 __attribute__((ext_vector_type(4)));
typedef __fp16 cvt2_t __attribute__((ext_vector_type(2)));
typedef float float4v __attribute__((ext_vector_type(4)));

struct CellW { const float *Wih, *Whh, *bih, *bhh; };
struct Params { CellW c[6]; const float* y; float* hout; };

__device__ __forceinline__ float fexp2(float x) { return __builtin_amdgcn_exp2f(x); }
__device__ __forceinline__ float frcp(float x)  { return __builtin_amdgcn_rcpf(x); }
__device__ __forceinline__ int packh(float a, float b) {
    cvt2_t p = __builtin_amdgcn_cvt_pkrtz(a, b);
    return __builtin_bit_cast(int, p);
}
__device__ __forceinline__ h4 mk(int lo, int hi) {
    int2 v; v.x = lo; v.y = hi;
    return __builtin_bit_cast(h4, v);
}

// K=16 MFMA (R0-proven layout): A[m][k], lane(n,Q) holds k=4Q..4Q+3; D lane
// (n,Q) reg r = row 4Q+r, col n. B-layout == D-layout -> recurrence needs
// only 2 packs. Split input-side/h-side so the input-side MFMA (depends only
// on hv/x, known for the whole round) can be issued 2 steps AHEAD, off the
// h-critical path; the h-side MFMA chains onto it via the C operand.
#define MFMA16(a, b, c) __builtin_amdgcn_mfma_f32_16x16x16f16(a, b, c, 0, 0, 0)

// Activation, 4 units/lane. pi,pf,po pre-scaled by -log2e, pg by -2log2e
// (folded into A/bias). c-path common-denominator fusion:
//   c' = f*c + i*g = (c*P + NG*F) / (F*P),  F=1+ef, P=(1+ei)(1+eg), NG=1-eg
// rcp PAIRED across independent unit chains: R=rcp(a*b); 1/a=R*b; 1/b=R*a.
// 4 rcp + 20 exp2 per call. Range audit (|pre| <= ~8 from weight bounds):
// F<=2^12, P<=2^35, den<=2^47, den-pair<=2^94 < 2^128. Dh<=2^42 (ec clamp
// 2^30), pair<2^84. No cancellation hazard: error in c' ~ eps*max(|fc|,|ig|).
__device__ __forceinline__ void act4(const float4v& pi, const float4v& pf,
                                     const float4v& pg, const float4v& po,
                                     float* cc, float* h) {
    float F[4], P[4], NG[4], den[4], num[4];
#pragma unroll
    for (int j = 0; j < 4; ++j) {
        float ei = fexp2(pi[j]);
        float ef = fexp2(pf[j]);
        float eg = fexp2(pg[j]);
        F[j]  = 1.f + ef;
        P[j]  = (1.f + ei) * (1.f + eg);
        NG[j] = 1.f - eg;
        den[j] = F[j] * P[j];
        num[j] = fmaf(cc[j], P[j], NG[j] * F[j]);
    }
    float RC01 = frcp(den[0] * den[1]);
    float RC23 = frcp(den[2] * den[3]);
    cc[0] = num[0] * den[1] * RC01;
    cc[1] = num[1] * den[0] * RC01;
    cc[2] = num[2] * den[3] * RC23;
    cc[3] = num[3] * den[2] * RC23;

    const float K2 = -2.8853900817779268f;     // -2*log2e
    float NO[4], Dh[4];
#pragma unroll
    for (int j = 0; j < 4; ++j) {
        float eo = fexp2(po[j]);
        float ec = fexp2(fminf(cc[j] * K2, 30.f));
        NO[j] = 1.f - ec;
        Dh[j] = (1.f + eo) * (1.f + ec);
    }
    float RH01 = frcp(Dh[0] * Dh[1]);
    float RH23 = frcp(Dh[2] * Dh[3]);
    h[0] = NO[0] * Dh[1] * RH01;
    h[1] = NO[1] * Dh[0] * RH01;
    h[2] = NO[2] * Dh[3] * RH23;
    h[3] = NO[3] * Dh[2] * RH23;
}

// Block = 3 waves = 3 layers of one 16-chain tile, skewed by 1 round.
// Barrier-paced rounds (R1's proven sync). Inner loop: 2-step-deep
// input-side MFMA pipeline fills the h-recurrence dependency shadow.
__global__ void __launch_bounds__(192)
__attribute__((amdgpu_waves_per_eu(1, 2)))
lstm_chain_kernel(Params p)
{
    __shared__ int2 lds_h[2][2][SPR][64];   // [producer][parity][k][lane] 16KB

    const int w = threadIdx.x >> 6;     // wave = layer
    const int L = threadIdx.x & 63;
    const int n = L & 15;               // batch col
    const int Q = L >> 4;

    const int tid = blockIdx.x;
    const int dir = tid & 1;
    const int b0  = (tid >> 1) * 16;

    const CellW cw = p.c[dir * 3 + w];
    const float LOG2E = 1.4426950408889634f;

    // ---- A-frags (m=n, k=4Q..4Q+3) + bias, activation scale folded ----
    h4 Aih[4], Ahh[4];
    float4v bs[4];
#pragma unroll
    for (int g = 0; g < 4; ++g) {
        const float s = (g == 2) ? -2.f * LOG2E : -LOG2E;
        const int row = g * 16 + n;
        float vi[4], vh[4];
#pragma unroll
        for (int i = 0; i < 4; ++i) {
            const int k = 4 * Q + i;
            vi[i] = (w == 0) ? ((Q == 0) ? cw.Wih[row * D_IN + k] : 0.f)
                             : cw.Wih[row * 16 + k];
            vh[i] = cw.Whh[row * 16 + k];
        }
        Aih[g] = mk(packh(vi[0] * s, vi[1] * s), packh(vi[2] * s, vi[3] * s));
        Ahh[g] = mk(packh(vh[0] * s, vh[1] * s), packh(vh[2] * s, vh[3] * s));
        const int u0 = g * 16 + 4 * Q;   // bias: reg r -> unit 4Q+r
        float4 bi = *(const float4*)&cw.bih[u0];
        float4 bh = *(const float4*)&cw.bhh[u0];
        bs[g] = (float4v){(bi.x+bh.x)*s, (bi.y+bh.y)*s, (bi.z+bh.z)*s, (bi.w+bh.w)*s};
    }

    // ---- x prefetch (wave 0, lanes L<16 = chain n); fed straight into B ----
    const float* ybase = p.y + (size_t)b0 * (T_LEN * D_IN);
    float4 xn[SPR];
    if (w == 0 && L < 16) {
#pragma unroll
        for (int k = 0; k < SPR; ++k) {
            const int tt = dir ? (T_LEN - 1 - k) : k;
            xn[k] = *(const float4*)(ybase + ((size_t)n * T_LEN + tt) * D_IN);
        }
    }

    float cc[4] = {0.f, 0.f, 0.f, 0.f};
    float h[4] = {0.f, 0.f, 0.f, 0.f};
    int hp0 = 0, hp1 = 0;               // packed own h (the B operand verbatim)

#pragma unroll 1
    for (int s = 0; s < NROUND; ++s) {
        __syncthreads();
        const int t0 = (s - w) * SPR;
        if (t0 < 0 || t0 >= T_LEN) continue;

        // ---- acquire round inputs into bv: x packs (w0) or prev-h (w1,w2)
        int2 bv[SPR];
        if (w == 0) {
            if (L < 16) {
#pragma unroll
                for (int k = 0; k < SPR; ++k) {
                    bv[k].x = packh(xn[k].x, xn[k].y);
                    bv[k].y = packh(xn[k].z, xn[k].w);
                }
                if (t0 + SPR < T_LEN) {
#pragma unroll
                    for (int k = 0; k < SPR; ++k) {
                        const int t = t0 + SPR + k;
                        const int tt = dir ? (T_LEN - 1 - t) : t;
                        xn[k] = *(const float4*)(ybase + ((size_t)n * T_LEN + tt) * D_IN);
                    }
                }
            } else {
#pragma unroll
                for (int k = 0; k < SPR; ++k) { bv[k].x = 0; bv[k].y = 0; }
            }
        } else {
#pragma unroll
            for (int k = 0; k < SPR; ++k)
                bv[k] = lds_h[w - 1][(s + 1) & 1][k][L];
        }

        // ---- input-side pipeline prologue: steps 0,1 (independent of own h)
        float4v pre[2][4];
#pragma unroll
        for (int g = 0; g < 4; ++g) {
            pre[0][g] = MFMA16(Aih[g], mk(bv[0].x, bv[0].y), bs[g]);
            pre[1][g] = MFMA16(Aih[g], mk(bv[1].x, bv[1].y), bs[g]);
        }

#pragma unroll
        for (int k = 0; k < SPR; ++k) {
            const h4 bh = mk(hp0, hp1);
            // h-side MFMA chains onto precomputed input-side C (slot k&1:
            // static under full unroll)
            float4v pi = MFMA16(Ahh[0], bh, pre[k & 1][0]);
            float4v pf = MFMA16(Ahh[1], bh, pre[k & 1][1]);
            float4v pg = MFMA16(Ahh[2], bh, pre[k & 1][2]);
            float4v po = MFMA16(Ahh[3], bh, pre[k & 1][3]);
            // refill slot for step k+2: independent work that fills the
            // act4/MFMA dependency shadow ((k+2)&1 == k&1)
            if (k + 2 < SPR) {
                const h4 bn = mk(bv[k + 2].x, bv[k + 2].y);
                pre[k & 1][0] = MFMA16(Aih[0], bn, bs[0]);
                pre[k & 1][1] = MFMA16(Aih[1], bn, bs[1]);
                pre[k & 1][2] = MFMA16(Aih[2], bn, bs[2]);
                pre[k & 1][3] = MFMA16(Aih[3], bn, bs[3]);
            }
            act4(pi, pf, pg, po, cc, h);
            hp0 = packh(h[0], h[1]);
            hp1 = packh(h[2], h[3]);
            if (w < 2) {
                int2 hw; hw.x = hp0; hw.y = hp1;
                lds_h[w][s & 1][k][L] = hw;
            }
        }
    }

    // wave 2 holds h3(T-1): lane (n,Q) has units 4Q..4Q+3, batch n
    if (w == 2) {
        float4v ho = {h[0], h[1], h[2], h[3]};
        *(float4v*)&p.hout[(size_t)(b0 + n) * 32 + dir * 16 + 4 * Q] = ho;
    }
}

__global__ void out_proj_kernel(const float* __restrict__ ws,
                                const float* __restrict__ Wout,
                                const float* __restrict__ bout,
                                float* __restrict__ out, int B)
{
    int idx = blockIdx.x * blockDim.x + threadIdx.x;
    if (idx >= B * 4) return;
    int b = idx >> 2, o = idx & 3;
    float acc = bout[o];
    const float* h = ws + (size_t)b * 32;
    const float* w = Wout + o * 32;
#pragma unroll
    for (int m = 0; m < 32; ++m) acc = fmaf(h[m], w[m], acc);
    out[idx] = acc;
}

extern "C" void kernel_launch(void* const* d_in, const int* in_sizes, int n_in,
                              void* d_out, int out_size, void* d_ws, size_t ws_size,
                              hipStream_t stream)
{
    const int B = in_sizes[0] / (T_LEN * D_IN); // 4096

    Params p;
    for (int s = 0; s < 6; ++s) {
        p.c[s].Wih = (const float*)d_in[1 + 4 * s];
        p.c[s].Whh = (const float*)d_in[2 + 4 * s];
        p.c[s].bih = (const float*)d_in[3 + 4 * s];
        p.c[s].bhh = (const float*)d_in[4 + 4 * s];
    }
    p.y = (const float*)d_in[0];
    p.hout = (float*)d_ws;

    const int tiles = (B / 16) * 2;          // 16 chains per tile, both dirs
    lstm_chain_kernel<<<tiles, 192, 0, stream>>>(p);

    const float* Wout = (const float*)d_in[25];
    const float* bout = (const float*)d_in[26];
    out_proj_kernel<<<(B * 4 + 255) / 256, 256, 0, stream>>>(
        (const float*)d_ws, Wout, bout, (float*)d_out, B);
}

// Round 5
// 270.691 us; speedup vs baseline: 1.0321x; 1.0132x over previous
//
#include <hip/hip_runtime.h>

#define T_LEN 256
#define D_IN 4
#define SPR 16                      // timesteps per barrier round
#define NROUND (T_LEN / SPR + 2)    // 18: layer skew 0..2

typedef __fp16 h8 __attribute__((ext_vector_type(8)));
typedef __fp16 cvt2_t __attribute__((ext_vector_type(2)));
typedef float float4v __attribute__((ext_vector_type(4)));

struct CellW { const float *Wih, *Whh, *bih, *bhh; };
struct Params { CellW c[6]; const float* y; float* hout; };

__device__ __forceinline__ float fexp2(float x) { return __builtin_amdgcn_exp2f(x); }
__device__ __forceinline__ float frcp(float x)  { return __builtin_amdgcn_rcpf(x); }
__device__ __forceinline__ int packh(float a, float b) {
    cvt2_t p = __builtin_amdgcn_cvt_pkrtz(a, b);
    return __builtin_bit_cast(int, p);
}
__device__ __forceinline__ h8 mk8(int a, int b, int c, int d) {
    int4 v; v.x = a; v.y = b; v.z = c; v.w = d;
    return __builtin_bit_cast(h8, v);
}

// K=32 MFMA (R1-proven): one instruction per gate. A = [Whh-cols | Wprev-cols]
// with the SAME per-lane element convention as B = {own-h packs, prev packs}.
// D layout: lane(n,Q) reg r = row 4Q+r, col n -> recurrence needs 2 packs.
#define MFMA32(a, b, c) __builtin_amdgcn_mfma_f32_16x16x32_f16(a, b, c, 0, 0, 0)

// Activation, 4 units/lane (R4-proven). pi,pf,po pre-scaled by -log2e, pg by
// -2log2e (folded into A/bias). c-path common-denominator fusion:
//   c' = f*c + i*g = (c*P + NG*F) / (F*P),  F=1+ef, P=(1+ei)(1+eg), NG=1-eg
// rcp PAIRED across independent unit chains: R=rcp(a*b); 1/a=R*b; 1/b=R*a.
// 4 rcp + 20 exp2 per call. Range audit (|pre| <= ~8): F<=2^12, P<=2^35,
// den<=2^47, den-pair<=2^94 < 2^128. Dh<=2^42 (ec clamp 2^30), pair<2^84.
// No cancellation hazard: error in c' ~ eps*max(|fc|,|ig|).
__device__ __forceinline__ void act4(const float4v& pi, const float4v& pf,
                                     const float4v& pg, const float4v& po,
                                     float* cc, float* h) {
    float F[4], P[4], NG[4], den[4], num[4];
#pragma unroll
    for (int j = 0; j < 4; ++j) {
        float ei = fexp2(pi[j]);
        float ef = fexp2(pf[j]);
        float eg = fexp2(pg[j]);
        F[j]  = 1.f + ef;
        P[j]  = (1.f + ei) * (1.f + eg);
        NG[j] = 1.f - eg;
        den[j] = F[j] * P[j];
        num[j] = fmaf(cc[j], P[j], NG[j] * F[j]);
    }
    float RC01 = frcp(den[0] * den[1]);
    float RC23 = frcp(den[2] * den[3]);
    cc[0] = num[0] * den[1] * RC01;
    cc[1] = num[1] * den[0] * RC01;
    cc[2] = num[2] * den[3] * RC23;
    cc[3] = num[3] * den[2] * RC23;

    const float K2 = -2.8853900817779268f;     // -2*log2e
    float NO[4], Dh[4];
#pragma unroll
    for (int j = 0; j < 4; ++j) {
        float eo = fexp2(po[j]);
        float ec = fexp2(fminf(cc[j] * K2, 30.f));
        NO[j] = 1.f - ec;
        Dh[j] = (1.f + eo) * (1.f + ec);
    }
    float RH01 = frcp(Dh[0] * Dh[1]);
    float RH23 = frcp(Dh[2] * Dh[3]);
    h[0] = NO[0] * Dh[1] * RH01;
    h[1] = NO[1] * Dh[0] * RH01;
    h[2] = NO[2] * Dh[3] * RH23;
    h[3] = NO[3] * Dh[2] * RH23;
}

// Block = 3 waves = 3 layers of one 16-chain tile, skewed by 1 round.
// Barrier-paced rounds; SPR=16 halves barrier count and per-round overhead
// vs SPR=8 (R1). Double-buffer parity protocol unchanged.
__global__ void __launch_bounds__(192)
__attribute__((amdgpu_waves_per_eu(1, 2)))
lstm_chain_kernel(Params p)
{
    __shared__ int2 lds_h[2][2][SPR][64];   // [producer][parity][k][lane] 32KB

    const int w = threadIdx.x >> 6;     // wave = layer
    const int L = threadIdx.x & 63;
    const int n = L & 15;               // batch col
    const int Q = L >> 4;

    const int tid = blockIdx.x;
    const int dir = tid & 1;
    const int b0  = (tid >> 1) * 16;

    const CellW cw = p.c[dir * 3 + w];
    const float LOG2E = 1.4426950408889634f;

    // ---- fused A-frags: elems 0-3 = Whh k=4Q..4Q+3, elems 4-7 = prev-side
    // (Wih for w>0; x-weights (Q==0)/zero for w==0). Scale folded. ----
    h8 A8[4];
    float4v bs[4];
#pragma unroll
    for (int g = 0; g < 4; ++g) {
        const float s = (g == 2) ? -2.f * LOG2E : -LOG2E;
        const int row = g * 16 + n;
        float vh[4], vp[4];
#pragma unroll
        for (int i = 0; i < 4; ++i) {
            const int k = 4 * Q + i;
            vh[i] = cw.Whh[row * 16 + k];
            vp[i] = (w == 0) ? ((Q == 0) ? cw.Wih[row * D_IN + k] : 0.f)
                             : cw.Wih[row * 16 + k];
        }
        A8[g] = mk8(packh(vh[0] * s, vh[1] * s), packh(vh[2] * s, vh[3] * s),
                    packh(vp[0] * s, vp[1] * s), packh(vp[2] * s, vp[3] * s));
        const int u0 = g * 16 + 4 * Q;   // bias: reg r -> unit 4Q+r
        float4 bi = *(const float4*)&cw.bih[u0];
        float4 bh = *(const float4*)&cw.bhh[u0];
        bs[g] = (float4v){(bi.x+bh.x)*s, (bi.y+bh.y)*s, (bi.z+bh.z)*s, (bi.w+bh.w)*s};
    }

    // ---- x prefetch (wave 0, lanes L<16 = chain n), packed to f16 at load
    // time to keep register cost at 2 VGPR/step ----
    const float* ybase = p.y + (size_t)b0 * (T_LEN * D_IN);
    int2 xn[SPR];
    if (w == 0 && L < 16) {
#pragma unroll
        for (int k = 0; k < SPR; ++k) {
            const int tt = dir ? (T_LEN - 1 - k) : k;
            float4 t = *(const float4*)(ybase + ((size_t)n * T_LEN + tt) * D_IN);
            xn[k].x = packh(t.x, t.y);
            xn[k].y = packh(t.z, t.w);
        }
    }

    float cc[4] = {0.f, 0.f, 0.f, 0.f};
    float h[4] = {0.f, 0.f, 0.f, 0.f};
    int hp0 = 0, hp1 = 0;               // packed own h (B elems 0-1 verbatim)

#pragma unroll 1
    for (int s = 0; s < NROUND; ++s) {
        __syncthreads();
        const int t0 = (s - w) * SPR;
        if (t0 < 0 || t0 >= T_LEN) continue;

        // ---- acquire round inputs into bv: x packs (w0) or prev-h (w1,w2)
        int2 bv[SPR];
        if (w == 0) {
            if (L < 16) {
#pragma unroll
                for (int k = 0; k < SPR; ++k) bv[k] = xn[k];
                if (t0 + SPR < T_LEN) {
#pragma unroll
                    for (int k = 0; k < SPR; ++k) {
                        const int t = t0 + SPR + k;
                        const int tt = dir ? (T_LEN - 1 - t) : t;
                        float4 x = *(const float4*)(ybase + ((size_t)n * T_LEN + tt) * D_IN);
                        xn[k].x = packh(x.x, x.y);
                        xn[k].y = packh(x.z, x.w);
                    }
                }
            } else {
#pragma unroll
                for (int k = 0; k < SPR; ++k) { bv[k].x = 0; bv[k].y = 0; }
            }
        } else {
#pragma unroll
            for (int k = 0; k < SPR; ++k)
                bv[k] = lds_h[w - 1][(s + 1) & 1][k][L];
        }

#pragma unroll
        for (int k = 0; k < SPR; ++k) {
            const h8 b8 = mk8(hp0, hp1, bv[k].x, bv[k].y);
            float4v pi = MFMA32(A8[0], b8, bs[0]);
            float4v pf = MFMA32(A8[1], b8, bs[1]);
            float4v pg = MFMA32(A8[2], b8, bs[2]);
            float4v po = MFMA32(A8[3], b8, bs[3]);
            act4(pi, pf, pg, po, cc, h);
            hp0 = packh(h[0], h[1]);
            hp1 = packh(h[2], h[3]);
            if (w < 2) {
                int2 hw; hw.x = hp0; hw.y = hp1;
                lds_h[w][s & 1][k][L] = hw;
            }
        }
    }

    // wave 2 holds h3(T-1): lane (n,Q) has units 4Q..4Q+3, batch n
    if (w == 2) {
        float4v ho = {h[0], h[1], h[2], h[3]};
        *(float4v*)&p.hout[(size_t)(b0 + n) * 32 + dir * 16 + 4 * Q] = ho;
    }
}

__global__ void out_proj_kernel(const float* __restrict__ ws,
                                const float* __restrict__ Wout,
                                const float* __restrict__ bout,
                                float* __restrict__ out, int B)
{
    int idx = blockIdx.x * blockDim.x + threadIdx.x;
    if (idx >= B * 4) return;
    int b = idx >> 2, o = idx & 3;
    float acc = bout[o];
    const float* h = ws + (size_t)b * 32;
    const float* w = Wout + o * 32;
#pragma unroll
    for (int m = 0; m < 32; ++m) acc = fmaf(h[m], w[m], acc);
    out[idx] = acc;
}

extern "C" void kernel_launch(void* const* d_in, const int* in_sizes, int n_in,
                              void* d_out, int out_size, void* d_ws, size_t ws_size,
                              hipStream_t stream)
{
    const int B = in_sizes[0] / (T_LEN * D_IN); // 4096

    Params p;
    for (int s = 0; s < 6; ++s) {
        p.c[s].Wih = (const float*)d_in[1 + 4 * s];
        p.c[s].Whh = (const float*)d_in[2 + 4 * s];
        p.c[s].bih = (const float*)d_in[3 + 4 * s];
        p.c[s].bhh = (const float*)d_in[4 + 4 * s];
    }
    p.y = (const float*)d_in[0];
    p.hout = (float*)d_ws;

    const int tiles = (B / 16) * 2;          // 16 chains per tile, both dirs
    lstm_chain_kernel<<<tiles, 192, 0, stream>>>(p);

    const float* Wout = (const float*)d_in[25];
    const float* bout = (const float*)d_in[26];
    out_proj_kernel<<<(B * 4 + 255) / 256, 256, 0, stream>>>(
        (const float*)d_ws, Wout, bout, (float*)d_out, B);
}

// Round 6
// 260.704 us; speedup vs baseline: 1.0717x; 1.0383x over previous
//
#include <hip/hip_runtime.h>

#define T_LEN 256
#define D_IN 4
#define NSTEP (T_LEN + 2)           // wavefront steps incl. layer skew 0..2

typedef __fp16 h8 __attribute__((ext_vector_type(8)));
typedef __fp16 cvt2_t __attribute__((ext_vector_type(2)));
typedef float float4v __attribute__((ext_vector_type(4)));

struct CellW { const float *Wih, *Whh, *bih, *bhh; };
struct Params { CellW c[6]; const float* y; float* hout; };

__device__ __forceinline__ float fexp2(float x) { return __builtin_amdgcn_exp2f(x); }
__device__ __forceinline__ float frcp(float x)  { return __builtin_amdgcn_rcpf(x); }
__device__ __forceinline__ int packh(float a, float b) {
    cvt2_t p = __builtin_amdgcn_cvt_pkrtz(a, b);
    return __builtin_bit_cast(int, p);
}
__device__ __forceinline__ h8 mk8(int a, int b, int c, int d) {
    int4 v; v.x = a; v.y = b; v.z = c; v.w = d;
    return __builtin_bit_cast(h8, v);
}

// K=32 MFMA, unit-gate-packed A (derived from R0/R1-proven layouts):
//   A lane(n,Q) holds A[row=n][k=4Q..4Q+3 | 16+4Q..16+4Q+3]
//   A row m  -> (local unit m>>2, gate m&3) of this MFMA's 4-unit group
//   D lane(n,Q) reg r = row 4Q+r -> gate r of local unit Q, batch col n
//   B lane(n,Q): elems 0-3 = own-h units 4Q..4Q+3, elems 4-7 = prev units
// So ONE MFMA yields all 4 gate preacts for 4 units, landing the full
// (i,f,g,o) of one unit in one lane's 4 regs.
#define MFMA32(a, b, c) __builtin_amdgcn_mfma_f32_16x16x32_f16(a, b, c, 0, 0, 0)

// Activation for 2 units (gate vecs pA, pB). p[0]=i,p[1]=f,p[2]=g,p[3]=o,
// pre-scaled by -log2e (i,f,o) / -2log2e (g), folded into A/bias.
// c-path common-denominator fusion (R4/R5-proven):
//   c' = (c*P + NG*F)/(F*P); F=1+ef, P=(1+ei)(1+eg), NG=1-eg
// rcp paired across the 2 units. 10 exp2 + 2 rcp per call (6 trans/unit).
// Range audit (|pre| <= ~8): den<=2^47, pair<=2^94 < 2^128; Dh<=2^42
// (ec clamp 2^30), pair<2^84. No cancellation: err(c') ~ eps*max|fc|,|ig|.
__device__ __forceinline__ void act2(const float4v& pA, const float4v& pB,
                                     float& cA, float& cB,
                                     float& hA, float& hB) {
    float eiA = fexp2(pA[0]), efA = fexp2(pA[1]), egA = fexp2(pA[2]);
    float eiB = fexp2(pB[0]), efB = fexp2(pB[1]), egB = fexp2(pB[2]);
    float FA = 1.f + efA,              FB = 1.f + efB;
    float PA = (1.f + eiA) * (1.f + egA), PB = (1.f + eiB) * (1.f + egB);
    float NGA = 1.f - egA,             NGB = 1.f - egB;
    float denA = FA * PA,              denB = FB * PB;
    float numA = fmaf(cA, PA, NGA * FA);
    float numB = fmaf(cB, PB, NGB * FB);
    float RC = frcp(denA * denB);
    cA = numA * denB * RC;
    cB = numB * denA * RC;
    const float K2 = -2.8853900817779268f;     // -2*log2e
    float eoA = fexp2(pA[3]), ecA = fexp2(fminf(cA * K2, 30.f));
    float eoB = fexp2(pB[3]), ecB = fexp2(fminf(cB * K2, 30.f));
    float NOA = 1.f - ecA,    NOB = 1.f - ecB;
    float DhA = (1.f + eoA) * (1.f + ecA);
    float DhB = (1.f + eoB) * (1.f + ecB);
    float RH = frcp(DhA * DhB);
    hA = NOA * DhB * RH;
    hB = NOB * DhA * RH;
}

// Wavefront kernel: block = 6 waves = 3 layers x 2 unit-halves of ONE
// 16-chain tile+dir. 512 blocks -> 12 waves/CU -> 3/SIMD UNIFORM (fixes the
// 2,2,1,1 pace imbalance that pinned R1/R2/R4/R5 at ~70% duty) and gives 3
// independent trans streams per SIMD to fill dependency latency.
// Recurrence h goes through a parity-double-buffered LDS array with ONE
// __syncthreads per timestep (safe barrier protocol; read buf[(s+1)&1],
// write buf[s&1] -> disjoint). x pre-packed to f16 LDS in a block prepass.
__global__ void __launch_bounds__(384)
__attribute__((amdgpu_waves_per_eu(3, 4)))
lstm_wf_kernel(Params p)
{
    __shared__ int2 x_lds[T_LEN][16];                       // 32 KB packed x
    __shared__ __align__(16) __fp16 h_lds[2][3][16][16];    // 3 KB h state

    const int tid = threadIdx.x;
    const int v = tid >> 6;         // wave 0..5
    const int l = v >> 1;           // layer 0..2
    const int e = v & 1;            // unit-half: units 8e..8e+7
    const int L = tid & 63;
    const int n = L & 15;           // batch col
    const int Q = L >> 4;

    const int dir = blockIdx.x & 1;
    const int b0  = (blockIdx.x >> 1) * 16;
    const CellW cw = p.c[dir * 3 + l];
    const float LOG2E = 1.4426950408889634f;

    // ---- prepass: zero h state (both parities), pack x tile to f16 ----
    for (int i = tid; i < (int)(sizeof(h_lds) / 4); i += 384)
        ((int*)h_lds)[i] = 0;
    for (int i = tid; i < T_LEN * 16; i += 384) {
        const int t = i >> 4, nn = i & 15;
        const int tt = dir ? (T_LEN - 1 - t) : t;
        const float4 xv = *(const float4*)(p.y +
            ((size_t)(b0 + nn) * T_LEN + tt) * D_IN);
        int2 xp; xp.x = packh(xv.x, xv.y); xp.y = packh(xv.z, xv.w);
        x_lds[t][nn] = xp;
    }

    // ---- A-frags: row n -> (local unit n>>2, gate n&3); 2 MFMAs cover the
    // half's 8 units. elems 0-3 = Whh cols 4Q..4Q+3, 4-7 = prev-side. ----
    const int gate = n & 3;
    const int su = n >> 2;
    const float sA = (gate == 2) ? -2.f * LOG2E : -LOG2E;
    h8 A8[2];
    float4v bs[2];
#pragma unroll
    for (int j = 0; j < 2; ++j) {
        const int u = 8 * e + 4 * j + su;   // A-row unit
        const int row = gate * 16 + u;
        float vh[4], vp[4];
#pragma unroll
        for (int i = 0; i < 4; ++i) {
            const int k = 4 * Q + i;
            vh[i] = cw.Whh[row * 16 + k];
            vp[i] = (l == 0) ? ((Q == 0) ? cw.Wih[row * D_IN + i] : 0.f)
                             : cw.Wih[row * 16 + k];
        }
        A8[j] = mk8(packh(vh[0] * sA, vh[1] * sA), packh(vh[2] * sA, vh[3] * sA),
                    packh(vp[0] * sA, vp[1] * sA), packh(vp[2] * sA, vp[3] * sA));
        const int ub = 8 * e + 4 * j + Q;   // D reg r = gate r of unit ub
        const float br0 = cw.bih[0 * 16 + ub] + cw.bhh[0 * 16 + ub];
        const float br1 = cw.bih[1 * 16 + ub] + cw.bhh[1 * 16 + ub];
        const float br2 = cw.bih[2 * 16 + ub] + cw.bhh[2 * 16 + ub];
        const float br3 = cw.bih[3 * 16 + ub] + cw.bhh[3 * 16 + ub];
        bs[j] = (float4v){br0 * -LOG2E, br1 * -LOG2E,
                          br2 * -2.f * LOG2E, br3 * -LOG2E};
    }

    __syncthreads();                 // prepass visible to all waves

    float cA = 0.f, cB = 0.f;        // cell state: units 8e+Q, 8e+4+Q
    float hA = 0.f, hB = 0.f;

#pragma unroll 1
    for (int s = 0; s < NSTEP; ++s) {
        if (s >= l && s - l < T_LEN) {
            const int t = s - l;
            const int pr = (s + 1) & 1;                 // read parity
            const int2 hown = *(const int2*)&h_lds[pr][l][n][4 * Q];
            int2 hprev;
            if (l == 0) {
                const int2 xv = x_lds[t][n];            // uniform in Q: bcast
                hprev.x = (Q == 0) ? xv.x : 0;
                hprev.y = (Q == 0) ? xv.y : 0;
            } else {
                hprev = *(const int2*)&h_lds[pr][l - 1][n][4 * Q];
            }
            const h8 b8 = mk8(hown.x, hown.y, hprev.x, hprev.y);
            float4v p0 = MFMA32(A8[0], b8, bs[0]);      // gates of unit 8e+Q
            float4v p1 = MFMA32(A8[1], b8, bs[1]);      // gates of unit 8e+4+Q
            act2(p0, p1, cA, cB, hA, hB);
            const int pw = s & 1;                       // write parity
            h_lds[pw][l][n][8 * e + Q]     = (__fp16)hA;
            h_lds[pw][l][n][8 * e + 4 + Q] = (__fp16)hB;
        }
        __syncthreads();
    }

    // layer-2 waves hold h3(T-1)
    if (l == 2) {
        float* o = p.hout + (size_t)(b0 + n) * 32 + dir * 16;
        o[8 * e + Q]     = hA;
        o[8 * e + 4 + Q] = hB;
    }
}

__global__ void out_proj_kernel(const float* __restrict__ ws,
                                const float* __restrict__ Wout,
                                const float* __restrict__ bout,
                                float* __restrict__ out, int B)
{
    int idx = blockIdx.x * blockDim.x + threadIdx.x;
    if (idx >= B * 4) return;
    int b = idx >> 2, o = idx & 3;
    float acc = bout[o];
    const float* h = ws + (size_t)b * 32;
    const float* w = Wout + o * 32;
#pragma unroll
    for (int m = 0; m < 32; ++m) acc = fmaf(h[m], w[m], acc);
    out[idx] = acc;
}

extern "C" void kernel_launch(void* const* d_in, const int* in_sizes, int n_in,
                              void* d_out, int out_size, void* d_ws, size_t ws_size,
                              hipStream_t stream)
{
    const int B = in_sizes[0] / (T_LEN * D_IN); // 4096

    Params p;
    for (int s = 0; s < 6; ++s) {
        p.c[s].Wih = (const float*)d_in[1 + 4 * s];
        p.c[s].Whh = (const float*)d_in[2 + 4 * s];
        p.c[s].bih = (const float*)d_in[3 + 4 * s];
        p.c[s].bhh = (const float*)d_in[4 + 4 * s];
    }
    p.y = (const float*)d_in[0];
    p.hout = (float*)d_ws;

    const int blocks = (B / 16) * 2;         // 16 chains per block, both dirs
    lstm_wf_kernel<<<blocks, 384, 0, stream>>>(p);

    const float* Wout = (const float*)d_in[25];
    const float* bout = (const float*)d_in[26];
    out_proj_kernel<<<(B * 4 + 255) / 256, 256, 0, stream>>>(
        (const float*)d_ws, Wout, bout, (float*)d_out, B);
}

// Round 7
// 257.429 us; speedup vs baseline: 1.0853x; 1.0127x over previous
//
#include <hip/hip_runtime.h>

#define T_LEN 256
#define D_IN 4
#define NSTEP (T_LEN + 2)           // wavefront steps incl. layer skew 0..2

typedef __fp16 h8 __attribute__((ext_vector_type(8)));
typedef __fp16 cvt2_t __attribute__((ext_vector_type(2)));
typedef float float4v __attribute__((ext_vector_type(4)));

struct CellW { const float *Wih, *Whh, *bih, *bhh; };
struct Params { CellW c[6]; const float* y; float* hout; };

__device__ __forceinline__ float fexp2(float x) { return __builtin_amdgcn_exp2f(x); }
__device__ __forceinline__ float frcp(float x)  { return __builtin_amdgcn_rcpf(x); }
__device__ __forceinline__ int packh(float a, float b) {
    cvt2_t p = __builtin_amdgcn_cvt_pkrtz(a, b);
    return __builtin_bit_cast(int, p);
}
__device__ __forceinline__ h8 mk8(int a, int b, int c, int d) {
    int4 v; v.x = a; v.y = b; v.z = c; v.w = d;
    return __builtin_bit_cast(h8, v);
}

// K=32 MFMA, unit-gate-packed A (R6-proven):
//   A row m -> (local unit m>>2, gate m&3); D lane(n,Q) reg r = gate r of
//   local unit Q, batch col n. MFMA j covers global units 8e+4j+Q.
// NEW (R7): input-column permutation pi: k-slot 4Q+i <-> input unit 4i+Q,
// applied identically to Whh (elems 0-3) and Wih l>0 (elems 4-7). This makes
// the B operand's elems 0-3 equal to exactly TWO writer-packed dwords:
//   D(0,Q) = (h[Q],   h[4+Q])  = slots 4Q+0, 4Q+1
//   D(1,Q) = (h[8+Q], h[12+Q]) = slots 4Q+2, 4Q+3
// so the h exchange is 1 b32 write + 2 b32 reads per lane, all 2-way banked
// (free). pi is an exact reindex of the dot product -> bitwise identical.
#define MFMA32(a, b, c) __builtin_amdgcn_mfma_f32_16x16x32_f16(a, b, c, 0, 0, 0)

// Activation for 2 units (R6-proven). p[0..3]=i,f,g,o pre-scaled by -log2e
// (i,f,o) / -2log2e (g), folded into A/bias. c-path common-denominator
// fusion, rcp paired across the 2 units: 10 exp2 + 2 rcp per call.
// Range audit (|pre| <= ~8): den<=2^47, pair<=2^94 < 2^128; Dh<=2^42
// (ec clamp 2^30), pair<2^84. No cancellation: err(c') ~ eps*max|fc|,|ig|.
__device__ __forceinline__ void act2(const float4v& pA, const float4v& pB,
                                     float& cA, float& cB,
                                     float& hA, float& hB) {
    float eiA = fexp2(pA[0]), efA = fexp2(pA[1]), egA = fexp2(pA[2]);
    float eiB = fexp2(pB[0]), efB = fexp2(pB[1]), egB = fexp2(pB[2]);
    float FA = 1.f + efA,              FB = 1.f + efB;
    float PA = (1.f + eiA) * (1.f + egA), PB = (1.f + eiB) * (1.f + egB);
    float NGA = 1.f - egA,             NGB = 1.f - egB;
    float denA = FA * PA,              denB = FB * PB;
    float numA = fmaf(cA, PA, NGA * FA);
    float numB = fmaf(cB, PB, NGB * FB);
    float RC = frcp(denA * denB);
    cA = numA * denB * RC;
    cB = numB * denA * RC;
    const float K2 = -2.8853900817779268f;     // -2*log2e
    float eoA = fexp2(pA[3]), ecA = fexp2(fminf(cA * K2, 30.f));
    float eoB = fexp2(pB[3]), ecB = fexp2(fminf(cB * K2, 30.f));
    float NOA = 1.f - ecA,    NOB = 1.f - ecB;
    float DhA = (1.f + eoA) * (1.f + ecA);
    float DhB = (1.f + eoB) * (1.f + ecB);
    float RH = frcp(DhA * DhB);
    hA = NOA * DhB * RH;
    hB = NOB * DhA * RH;
}

// Wavefront kernel: block = 6 waves = 3 layers x 2 unit-halves of ONE
// 16-chain tile+dir. 512 blocks -> 12 waves/CU -> 3/SIMD uniform.
// h exchange via conflict-free packed-dword LDS (see pi above), parity
// double-buffered, one __syncthreads per timestep (read (s+1)&1, write s&1).
__global__ void __launch_bounds__(384)
__attribute__((amdgpu_waves_per_eu(3, 4)))
lstm_wf_kernel(Params p)
{
    __shared__ int2 x_lds[T_LEN][16];          // 32 KB packed x
    __shared__ int h_pk[2][3][2][4][16];       // 3 KB [par][layer][e][Q][n]

    const int tid = threadIdx.x;
    const int v = tid >> 6;         // wave 0..5
    const int l = v >> 1;           // layer 0..2
    const int e = v & 1;            // unit-half: units 8e..8e+7
    const int L = tid & 63;
    const int n = L & 15;           // batch col
    const int Q = L >> 4;

    const int dir = blockIdx.x & 1;
    const int b0  = (blockIdx.x >> 1) * 16;
    const CellW cw = p.c[dir * 3 + l];
    const float LOG2E = 1.4426950408889634f;

    // ---- prepass: zero h state (both parities), pack x tile to f16 ----
    for (int i = tid; i < 2 * 3 * 2 * 4 * 16; i += 384)
        ((int*)h_pk)[i] = 0;
    for (int i = tid; i < T_LEN * 16; i += 384) {
        const int t = i >> 4, nn = i & 15;
        const int tt = dir ? (T_LEN - 1 - t) : t;
        const float4 xv = *(const float4*)(p.y +
            ((size_t)(b0 + nn) * T_LEN + tt) * D_IN);
        int2 xp; xp.x = packh(xv.x, xv.y); xp.y = packh(xv.z, xv.w);
        x_lds[t][nn] = xp;
    }

    // ---- A-frags: row n -> (local unit n>>2, gate n&3); columns permuted
    // by pi (slot 4Q+i <-> input unit 4i+Q). Layer-0 x-columns natural. ----
    const int gate = n & 3;
    const int su = n >> 2;
    const float sA = (gate == 2) ? -2.f * LOG2E : -LOG2E;
    h8 A8[2];
    float4v bs[2];
#pragma unroll
    for (int j = 0; j < 2; ++j) {
        const int u = 8 * e + 4 * j + su;   // A-row unit
        const int row = gate * 16 + u;
        float vh[4], vp[4];
#pragma unroll
        for (int i = 0; i < 4; ++i) {
            const int col = 4 * i + Q;      // pi-permuted input unit
            vh[i] = cw.Whh[row * 16 + col];
            vp[i] = (l == 0) ? ((Q == 0) ? cw.Wih[row * D_IN + i] : 0.f)
                             : cw.Wih[row * 16 + col];
        }
        A8[j] = mk8(packh(vh[0] * sA, vh[1] * sA), packh(vh[2] * sA, vh[3] * sA),
                    packh(vp[0] * sA, vp[1] * sA), packh(vp[2] * sA, vp[3] * sA));
        const int ub = 8 * e + 4 * j + Q;   // D reg r = gate r of unit ub
        const float br0 = cw.bih[0 * 16 + ub] + cw.bhh[0 * 16 + ub];
        const float br1 = cw.bih[1 * 16 + ub] + cw.bhh[1 * 16 + ub];
        const float br2 = cw.bih[2 * 16 + ub] + cw.bhh[2 * 16 + ub];
        const float br3 = cw.bih[3 * 16 + ub] + cw.bhh[3 * 16 + ub];
        bs[j] = (float4v){br0 * -LOG2E, br1 * -LOG2E,
                          br2 * -2.f * LOG2E, br3 * -LOG2E};
    }

    __syncthreads();                 // prepass visible to all waves

    float cA = 0.f, cB = 0.f;        // cell state: units 8e+Q, 8e+4+Q
    float hA = 0.f, hB = 0.f;

#pragma unroll 1
    for (int s = 0; s < NSTEP; ++s) {
        if (s >= l && s - l < T_LEN) {
            const int t = s - l;
            const int pr = (s + 1) & 1;                 // read parity
            // own h: two packed dwords D(0,Q), D(1,Q) -- 2-way banked
            const int* hsO = &h_pk[pr][l][0][Q][n];
            const int o0 = hsO[0];
            const int o1 = hsO[64];                     // e=1 plane, +256B
            int pd0, pd1;
            if (l == 0) {
                const int2 xv = x_lds[t][n];            // uniform in Q: bcast
                pd0 = (Q == 0) ? xv.x : 0;
                pd1 = (Q == 0) ? xv.y : 0;
            } else {
                const int* hsP = &h_pk[pr][l - 1][0][Q][n];
                pd0 = hsP[0];
                pd1 = hsP[64];
            }
            const h8 b8 = mk8(o0, o1, pd0, pd1);
            float4v p0 = MFMA32(A8[0], b8, bs[0]);      // gates of unit 8e+Q
            float4v p1 = MFMA32(A8[1], b8, bs[1]);      // gates of unit 8e+4+Q
            act2(p0, p1, cA, cB, hA, hB);
            const int pw = s & 1;                       // write parity
            h_pk[pw][l][e][Q][n] = packh(hA, hB);       // one b32, 2-way
        }
        __syncthreads();
    }

    // layer-2 waves hold h3(T-1): units 8e+Q, 8e+4+Q of chain n
    if (l == 2) {
        float* o = p.hout + (size_t)(b0 + n) * 32 + dir * 16;
        o[8 * e + Q]     = hA;
        o[8 * e + 4 + Q] = hB;
    }
}

__global__ void out_proj_kernel(const float* __restrict__ ws,
                                const float* __restrict__ Wout,
                                const float* __restrict__ bout,
                                float* __restrict__ out, int B)
{
    int idx = blockIdx.x * blockDim.x + threadIdx.x;
    if (idx >= B * 4) return;
    int b = idx >> 2, o = idx & 3;
    float acc = bout[o];
    const float* h = ws + (size_t)b * 32;
    const float* w = Wout + o * 32;
#pragma unroll
    for (int m = 0; m < 32; ++m) acc = fmaf(h[m], w[m], acc);
    out[idx] = acc;
}

extern "C" void kernel_launch(void* const* d_in, const int* in_sizes, int n_in,
                              void* d_out, int out_size, void* d_ws, size_t ws_size,
                              hipStream_t stream)
{
    const int B = in_sizes[0] / (T_LEN * D_IN); // 4096

    Params p;
    for (int s = 0; s < 6; ++s) {
        p.c[s].Wih = (const float*)d_in[1 + 4 * s];
        p.c[s].Whh = (const float*)d_in[2 + 4 * s];
        p.c[s].bih = (const float*)d_in[3 + 4 * s];
        p.c[s].bhh = (const float*)d_in[4 + 4 * s];
    }
    p.y = (const float*)d_in[0];
    p.hout = (float*)d_ws;

    const int blocks = (B / 16) * 2;         // 16 chains per block, both dirs
    lstm_wf_kernel<<<blocks, 384, 0, stream>>>(p);

    const float* Wout = (const float*)d_in[25];
    const float* bout = (const float*)d_in[26];
    out_proj_kernel<<<(B * 4 + 255) / 256, 256, 0, stream>>>(
        (const float*)d_ws, Wout, bout, (float*)d_out, B);
}

// Round 8
// 243.186 us; speedup vs baseline: 1.1488x; 1.0586x over previous
//
#include <hip/hip_runtime.h>

#define T_LEN 256
#define D_IN 4
#define NSTEP (T_LEN + 2)           // wavefront steps incl. layer skew 0..2

typedef __fp16 h8 __attribute__((ext_vector_type(8)));
typedef __fp16 cvt2_t __attribute__((ext_vector_type(2)));
typedef float float4v __attribute__((ext_vector_type(4)));

struct CellW { const float *Wih, *Whh, *bih, *bhh; };
struct Params { CellW c[6]; const float* y; float* hout; };

__device__ __forceinline__ float fexp2(float x) { return __builtin_amdgcn_exp2f(x); }
__device__ __forceinline__ float frcp(float x)  { return __builtin_amdgcn_rcpf(x); }
__device__ __forceinline__ int packh(float a, float b) {
    cvt2_t p = __builtin_amdgcn_cvt_pkrtz(a, b);
    return __builtin_bit_cast(int, p);
}
__device__ __forceinline__ h8 mk8(int a, int b, int c, int d) {
    int4 v; v.x = a; v.y = b; v.z = c; v.w = d;
    return __builtin_bit_cast(h8, v);
}

// K=32 MFMA, unit-gate-packed A with pi input-column permutation (R7-proven):
//   A row m -> (local unit m>>2, gate m&3); D lane(n,Q) reg r = gate r of
//   local unit Q, batch col n. MFMA j covers global units 8e+4j+Q.
//   pi: k-slot 4Q+i <-> input unit 4i+Q (applied to Whh and Wih l>0), so the
//   B operand's elems 0-3 are exactly TWO writer-packed dwords; h exchange is
//   1 b32 write + 2 b32 reads per lane, all 2-way banked (free, 0 conflicts).
#define MFMA32(a, b, c) __builtin_amdgcn_mfma_f32_16x16x32_f16(a, b, c, 0, 0, 0)

// Activation for 2 units (R6/R7-proven). p[0..3]=i,f,g,o pre-scaled by -log2e
// (i,f,o) / -2log2e (g), folded into A/bias. c-path common-denominator
// fusion, rcp paired across the 2 units: 10 exp2 + 2 rcp per call.
// Range audit (|pre| <= ~8): den<=2^47, pair<=2^94 < 2^128; Dh<=2^42
// (ec clamp 2^30), pair<2^84. No cancellation: err(c') ~ eps*max|fc|,|ig|.
__device__ __forceinline__ void act2(const float4v& pA, const float4v& pB,
                                     float& cA, float& cB,
                                     float& hA, float& hB) {
    float eiA = fexp2(pA[0]), efA = fexp2(pA[1]), egA = fexp2(pA[2]);
    float eiB = fexp2(pB[0]), efB = fexp2(pB[1]), egB = fexp2(pB[2]);
    float FA = 1.f + efA,              FB = 1.f + efB;
    float PA = (1.f + eiA) * (1.f + egA), PB = (1.f + eiB) * (1.f + egB);
    float NGA = 1.f - egA,             NGB = 1.f - egB;
    float denA = FA * PA,              denB = FB * PB;
    float numA = fmaf(cA, PA, NGA * FA);
    float numB = fmaf(cB, PB, NGB * FB);
    float RC = frcp(denA * denB);
    cA = numA * denB * RC;
    cB = numB * denA * RC;
    const float K2 = -2.8853900817779268f;     // -2*log2e
    float eoA = fexp2(pA[3]), ecA = fexp2(fminf(cA * K2, 30.f));
    float eoB = fexp2(pB[3]), ecB = fexp2(fminf(cB * K2, 30.f));
    float NOA = 1.f - ecA,    NOB = 1.f - ecB;
    float DhA = (1.f + eoA) * (1.f + ecA);
    float DhB = (1.f + eoB) * (1.f + ecB);
    float RH = frcp(DhA * DhB);
    hA = NOA * DhB * RH;
    hB = NOB * DhA * RH;
}

// Wavefront kernel, 12-wave block: BOTH dirs of one 16-chain tile.
// 12 waves = 2 dirs x 3 layers x 2 unit-halves -> waves round-robin SIMDs
// -> every SIMD carries exactly 3 waves OF THE SAME BARRIER GROUP. This
// removes the within-block 2,2,1,1 imbalance that paced R1/R6/R7 (~58% duty):
// the per-step __syncthreads now converges 4 equally-loaded SIMDs.
// Grid = 256 = 1 block/CU; LDS padded >80KB so 2 blocks can never share a CU.
__global__ void __launch_bounds__(768)
__attribute__((amdgpu_waves_per_eu(3, 4)))
lstm_wf_kernel(Params p)
{
    __shared__ int2 x_lds[2][T_LEN][16];       // 64 KB packed x, per dir
    __shared__ int h_pk[2][2][3][2][4][16];    // 6 KB [dir][par][l][e][Q][n]
    __shared__ int pad_excl[3072];             // 12 KB: forces 1 block/CU

    const int tid = threadIdx.x;
    const int v = tid >> 6;         // wave 0..11
    const int half = (v >= 6);      // = dir
    const int v6 = v - 6 * half;
    const int l = v6 >> 1;          // layer 0..2
    const int e = v6 & 1;           // unit-half: units 8e..8e+7
    const int L = tid & 63;
    const int n = L & 15;           // batch col
    const int Q = L >> 4;

    const int b0 = blockIdx.x * 16;
    const CellW cw = p.c[half * 3 + l];
    const float LOG2E = 1.4426950408889634f;

    if (tid == 767) pad_excl[0] = tid;         // keep pad alive (occupancy cap)

    // ---- prepass: zero h state (both parities), pack x tile to f16 ----
    for (int i = tid; i < 2 * 2 * 3 * 2 * 4 * 16; i += 768)
        ((int*)h_pk)[i] = 0;
    for (int i = tid; i < 2 * T_LEN * 16; i += 768) {
        const int d = i >> 12;                 // dir plane (T_LEN*16 = 4096)
        const int r = i & 4095;
        const int t = r >> 4, nn = r & 15;
        const int tt = d ? (T_LEN - 1 - t) : t;
        const float4 xv = *(const float4*)(p.y +
            ((size_t)(b0 + nn) * T_LEN + tt) * D_IN);
        int2 xp; xp.x = packh(xv.x, xv.y); xp.y = packh(xv.z, xv.w);
        x_lds[d][t][nn] = xp;
    }

    // ---- A-frags: row n -> (local unit n>>2, gate n&3); columns permuted
    // by pi (slot 4Q+i <-> input unit 4i+Q). Layer-0 x-columns natural. ----
    const int gate = n & 3;
    const int su = n >> 2;
    const float sA = (gate == 2) ? -2.f * LOG2E : -LOG2E;
    h8 A8[2];
    float4v bs[2];
#pragma unroll
    for (int j = 0; j < 2; ++j) {
        const int u = 8 * e + 4 * j + su;   // A-row unit
        const int row = gate * 16 + u;
        float vh[4], vp[4];
#pragma unroll
        for (int i = 0; i < 4; ++i) {
            const int col = 4 * i + Q;      // pi-permuted input unit
            vh[i] = cw.Whh[row * 16 + col];
            vp[i] = (l == 0) ? ((Q == 0) ? cw.Wih[row * D_IN + i] : 0.f)
                             : cw.Wih[row * 16 + col];
        }
        A8[j] = mk8(packh(vh[0] * sA, vh[1] * sA), packh(vh[2] * sA, vh[3] * sA),
                    packh(vp[0] * sA, vp[1] * sA), packh(vp[2] * sA, vp[3] * sA));
        const int ub = 8 * e + 4 * j + Q;   // D reg r = gate r of unit ub
        const float br0 = cw.bih[0 * 16 + ub] + cw.bhh[0 * 16 + ub];
        const float br1 = cw.bih[1 * 16 + ub] + cw.bhh[1 * 16 + ub];
        const float br2 = cw.bih[2 * 16 + ub] + cw.bhh[2 * 16 + ub];
        const float br3 = cw.bih[3 * 16 + ub] + cw.bhh[3 * 16 + ub];
        bs[j] = (float4v){br0 * -LOG2E, br1 * -LOG2E,
                          br2 * -2.f * LOG2E, br3 * -LOG2E};
    }

    __syncthreads();                 // prepass visible to all waves

    float cA = 0.f, cB = 0.f;        // cell state: units 8e+Q, 8e+4+Q
    float hA = 0.f, hB = 0.f;

#pragma unroll 1
    for (int s = 0; s < NSTEP; ++s) {
        if (s >= l && s - l < T_LEN) {
            const int t = s - l;
            const int pr = (s + 1) & 1;                 // read parity
            // own h: two packed dwords (e=0 plane, e=1 plane) -- 2-way banked
            const int* hsO = &h_pk[half][pr][l][0][Q][n];
            const int o0 = hsO[0];
            const int o1 = hsO[64];
            int pd0, pd1;
            if (l == 0) {
                const int2 xv = x_lds[half][t][n];      // uniform in Q: bcast
                pd0 = (Q == 0) ? xv.x : 0;
                pd1 = (Q == 0) ? xv.y : 0;
            } else {
                const int* hsP = &h_pk[half][pr][l - 1][0][Q][n];
                pd0 = hsP[0];
                pd1 = hsP[64];
            }
            const h8 b8 = mk8(o0, o1, pd0, pd1);
            float4v p0 = MFMA32(A8[0], b8, bs[0]);      // gates of unit 8e+Q
            float4v p1 = MFMA32(A8[1], b8, bs[1]);      // gates of unit 8e+4+Q
            act2(p0, p1, cA, cB, hA, hB);
            const int pw = s & 1;                       // write parity
            h_pk[half][pw][l][e][Q][n] = packh(hA, hB); // one b32, 2-way
        }
        __syncthreads();
    }

    // layer-2 waves hold h3(T-1): units 8e+Q, 8e+4+Q of chain n
    if (l == 2) {
        float* o = p.hout + (size_t)(b0 + n) * 32 + half * 16;
        o[8 * e + Q]     = hA;
        o[8 * e + 4 + Q] = hB;
    }
}

__global__ void out_proj_kernel(const float* __restrict__ ws,
                                const float* __restrict__ Wout,
                                const float* __restrict__ bout,
                                float* __restrict__ out, int B)
{
    int idx = blockIdx.x * blockDim.x + threadIdx.x;
    if (idx >= B * 4) return;
    int b = idx >> 2, o = idx & 3;
    float acc = bout[o];
    const float* h = ws + (size_t)b * 32;
    const float* w = Wout + o * 32;
#pragma unroll
    for (int m = 0; m < 32; ++m) acc = fmaf(h[m], w[m], acc);
    out[idx] = acc;
}

extern "C" void kernel_launch(void* const* d_in, const int* in_sizes, int n_in,
                              void* d_out, int out_size, void* d_ws, size_t ws_size,
                              hipStream_t stream)
{
    const int B = in_sizes[0] / (T_LEN * D_IN); // 4096

    Params p;
    for (int s = 0; s < 6; ++s) {
        p.c[s].Wih = (const float*)d_in[1 + 4 * s];
        p.c[s].Whh = (const float*)d_in[2 + 4 * s];
        p.c[s].bih = (const float*)d_in[3 + 4 * s];
        p.c[s].bhh = (const float*)d_in[4 + 4 * s];
    }
    p.y = (const float*)d_in[0];
    p.hout = (float*)d_ws;

    const int blocks = B / 16;               // 16 chains + both dirs per block
    lstm_wf_kernel<<<blocks, 768, 0, stream>>>(p);

    const float* Wout = (const float*)d_in[25];
    const float* bout = (const float*)d_in[26];
    out_proj_kernel<<<(B * 4 + 255) / 256, 256, 0, stream>>>(
        (const float*)d_ws, Wout, bout, (float*)d_out, B);
}